// Round 1
// baseline (1759.922 us; speedup 1.0000x reference)
//
#include <hip/hip_runtime.h>
#include <hip/hip_bf16.h>

#define B_  8
#define C_  1024
#define HW_ 4096
#define NK  21

using bf16 = __hip_bfloat16;
typedef __attribute__((ext_vector_type(8))) short short8;
typedef __attribute__((ext_vector_type(4))) float float4_;

static __device__ __forceinline__ float bf2f(unsigned short u) {
    union { unsigned int i; float f; } v; v.i = ((unsigned int)u) << 16; return v.f;
}

// ---------------- kernel 1: per-pixel inverse norms --------------------------
__global__ __launch_bounds__(256) void knorm(const float* __restrict__ x4, float* __restrict__ rn) {
    int t = threadIdx.x;
    int blk = blockIdx.x;              // 128 blocks: 8 b * 16 j-tiles
    int b = blk >> 4;
    int j = ((blk & 15) << 8) + t;
    const float* p = x4 + (size_t)b * C_ * HW_ + j;
    float s = 0.f;
#pragma unroll 8
    for (int c = 0; c < C_; ++c) {
        float v = p[(size_t)c * HW_];
        s = fmaf(v, v, s);
    }
    rn[b * HW_ + j] = 1.0f / fmaxf(sqrtf(s), 1e-12f);
}

// ---------------- kernel 2: transpose + scale -> XnT[b][j][c] (bf16) ---------
__global__ __launch_bounds__(256) void ktrans(const float* __restrict__ x4, const float* __restrict__ rn,
                                              bf16* __restrict__ XnT) {
    int b = blockIdx.z, ct = blockIdx.y, jt = blockIdx.x;
    int c0 = ct * 32, j0 = jt * 32;
    int tx = threadIdx.x & 31, ty = threadIdx.x >> 5;   // 32 x 8
    __shared__ float tile[32][33];
#pragma unroll
    for (int r = 0; r < 4; ++r) {
        int c = c0 + ty + r * 8;
        tile[ty + r * 8][tx] = x4[((size_t)b * C_ + c) * HW_ + j0 + tx];
    }
    __syncthreads();
#pragma unroll
    for (int r = 0; r < 4; ++r) {
        int j = j0 + ty + r * 8;
        float s = rn[b * HW_ + j];
        XnT[((size_t)b * HW_ + j) * C_ + c0 + tx] = __float2bfloat16(tile[tx][ty + r * 8] * s);
    }
}

// ---------------- kernel 3: gram + clamp + threshold + colsum ----------------
// C = Xn^T Xn per batch; 128x128 tile per block, BK=64, 4 waves (2x2), each
// wave 64x64 via 4x4 frags of mfma_f32_16x16x32_bf16.
__global__ __launch_bounds__(256) void kgram(const bf16* __restrict__ XnT, bf16* __restrict__ aff,
                                             float* __restrict__ colsum) {
    int b = blockIdx.z, it = blockIdx.y, jt = blockIdx.x;
    int i0 = it * 128, j0 = jt * 128;
    int t = threadIdx.x, w = t >> 6, l = t & 63;
    int wr = w >> 1, wc = w & 1;
    int lrow = l & 15, lk = l >> 4;

    __shared__ __align__(16) bf16 As[128 * 64];
    __shared__ __align__(16) bf16 Bs[128 * 64];

    const bf16* XA = XnT + ((size_t)b * HW_ + i0) * C_;
    const bf16* XB = XnT + ((size_t)b * HW_ + j0) * C_;

    float4_ acc[4][4];
#pragma unroll
    for (int m = 0; m < 4; ++m)
#pragma unroll
        for (int n = 0; n < 4; ++n) acc[m][n] = {0.f, 0.f, 0.f, 0.f};

    for (int k0 = 0; k0 < C_; k0 += 64) {
        __syncthreads();
#pragma unroll
        for (int q = 0; q < 4; ++q) {
            int m = w * 4 + q;                 // chunk 0..15, uniform per wave
            int row = m * 8 + (l >> 3);
            int col = (l & 7) * 8;
            __builtin_amdgcn_global_load_lds(
                (const __attribute__((address_space(1))) void*)(XA + (size_t)row * C_ + k0 + col),
                (__attribute__((address_space(3))) void*)(As + m * 512), 16, 0, 0);
            __builtin_amdgcn_global_load_lds(
                (const __attribute__((address_space(1))) void*)(XB + (size_t)row * C_ + k0 + col),
                (__attribute__((address_space(3))) void*)(Bs + m * 512), 16, 0, 0);
        }
        __syncthreads();
#pragma unroll
        for (int ks = 0; ks < 2; ++ks) {
            int kb = ks * 32 + lk * 8;
            short8 av[4], bv[4];
#pragma unroll
            for (int m = 0; m < 4; ++m)
                av[m] = *(const short8*)(As + (wr * 64 + m * 16 + lrow) * 64 + kb);
#pragma unroll
            for (int n = 0; n < 4; ++n)
                bv[n] = *(const short8*)(Bs + (wc * 64 + n * 16 + lrow) * 64 + kb);
#pragma unroll
            for (int m = 0; m < 4; ++m)
#pragma unroll
                for (int n = 0; n < 4; ++n)
                    acc[m][n] = __builtin_amdgcn_mfma_f32_16x16x32_bf16(av[m], bv[n], acc[m][n], 0, 0, 0);
        }
    }

    // epilogue: clamp -> threshold -> bf16 store, colsum accumulation
    size_t affb = (size_t)b * HW_ * HW_;
#pragma unroll
    for (int n = 0; n < 4; ++n) {
        int j = j0 + wc * 64 + n * 16 + lrow;
        float cs = 0.f;
#pragma unroll
        for (int m = 0; m < 4; ++m) {
#pragma unroll
            for (int r = 0; r < 4; ++r) {
                float v = acc[m][n][r];
                v = fminf(fmaxf(v, 0.01f), 0.999f);
                v = (v < 0.5f) ? 0.0f : v;
                bf16 bb = __float2bfloat16(v);
                int i = i0 + wr * 64 + m * 16 + lk * 4 + r;
                aff[affb + (size_t)i * HW_ + j] = bb;
                cs += __bfloat162float(bb);
            }
        }
        cs += __shfl_xor(cs, 16);
        cs += __shfl_xor(cs, 32);
        if (lk == 0) atomicAdd(&colsum[b * HW_ + j], cs);
    }
}

// ---------------- kernel 4: U[k][j] += sum_i lf[k][i] * aff[i][j] ------------
__global__ __launch_bounds__(256) void kprop(const float* __restrict__ lf, const bf16* __restrict__ aff,
                                             float* __restrict__ U) {
    int b = blockIdx.z, is = blockIdx.y, jb = blockIdx.x;
    int t = threadIdx.x;
    int j = jb * 512 + t * 2;
    int ib0 = is * 1024;
    __shared__ float lfs[NK * 128];
    float2 acc[NK];
#pragma unroll
    for (int k = 0; k < NK; ++k) acc[k] = make_float2(0.f, 0.f);

    for (int c0 = 0; c0 < 8; ++c0) {
        int ibase = ib0 + c0 * 128;
        __syncthreads();
        for (int idx = t; idx < NK * 128; idx += 256)
            lfs[idx] = lf[((size_t)b * NK + (idx >> 7)) * HW_ + ibase + (idx & 127)];
        __syncthreads();
        const bf16* ap = aff + ((size_t)b * HW_ + ibase) * HW_ + j;
        for (int ii = 0; ii < 128; ++ii) {
            unsigned int av = *(const unsigned int*)(ap + (size_t)ii * HW_);
            if (av != 0u) {                       // near-diagonal aff: usually wave-uniform skip
                float a0 = bf2f((unsigned short)(av & 0xffffu));
                float a1 = bf2f((unsigned short)(av >> 16));
#pragma unroll
                for (int k = 0; k < NK; ++k) {
                    float lv = lfs[(k << 7) + ii];
                    acc[k].x = fmaf(lv, a0, acc[k].x);
                    acc[k].y = fmaf(lv, a1, acc[k].y);
                }
            }
        }
    }
#pragma unroll
    for (int k = 0; k < NK; ++k) {
        float* up = &U[((size_t)b * NK + k) * HW_ + j];
        atomicAdd(up, acc[k].x);
        atomicAdd(up + 1, acc[k].y);
    }
}

// ---------------- kernel 5: divide by column sum -----------------------------
__global__ __launch_bounds__(256) void kdiv(const float* __restrict__ U, const float* __restrict__ colsum,
                                            float* __restrict__ out) {
    int idx = blockIdx.x * 256 + threadIdx.x;
    if (idx >= B_ * NK * HW_) return;
    int b = idx / (NK * HW_);
    int j = idx & (HW_ - 1);
    out[idx] = U[idx] / colsum[b * HW_ + j];
}

extern "C" void kernel_launch(void* const* d_in, const int* in_sizes, int n_in,
                              void* d_out, int out_size, void* d_ws, size_t ws_size,
                              hipStream_t stream) {
    const float* x4 = (const float*)d_in[0];
    const float* logits = (const float*)d_in[1];
    float* out = (float*)d_out;

    char* w = (char*)d_ws;
    size_t off = 0;
    auto take = [&](size_t bytes) {
        char* p = w + off;
        off += (bytes + 255) & ~(size_t)255;
        return p;
    };
    bf16* XnT    = (bf16*)take((size_t)B_ * HW_ * C_ * 2);     //  64 MiB
    bf16* aff    = (bf16*)take((size_t)B_ * HW_ * HW_ * 2);    // 256 MiB
    float* rn    = (float*)take((size_t)B_ * HW_ * 4);
    float* colsum= (float*)take((size_t)B_ * HW_ * 4);
    float* U1    = (float*)take((size_t)B_ * NK * HW_ * 4);
    float* lf1   = (float*)take((size_t)B_ * NK * HW_ * 4);
    float* U2    = (float*)take((size_t)B_ * NK * HW_ * 4);

    hipMemsetAsync(colsum, 0, (size_t)B_ * HW_ * 4, stream);
    hipMemsetAsync(U1, 0, (size_t)B_ * NK * HW_ * 4, stream);
    hipMemsetAsync(U2, 0, (size_t)B_ * NK * HW_ * 4, stream);

    knorm <<<dim3(128), dim3(256), 0, stream>>>(x4, rn);
    ktrans<<<dim3(HW_ / 32, C_ / 32, B_), dim3(256), 0, stream>>>(x4, rn, XnT);
    kgram <<<dim3(HW_ / 128, HW_ / 128, B_), dim3(256), 0, stream>>>(XnT, aff, colsum);

    // pcm = 2 propagation rounds (pcm input is a compile-time-known scalar = 2)
    kprop<<<dim3(8, 4, B_), dim3(256), 0, stream>>>(logits, aff, U1);
    kdiv <<<dim3((B_ * NK * HW_ + 255) / 256), dim3(256), 0, stream>>>(U1, colsum, lf1);
    kprop<<<dim3(8, 4, B_), dim3(256), 0, stream>>>(lf1, aff, U2);
    kdiv <<<dim3((B_ * NK * HW_ + 255) / 256), dim3(256), 0, stream>>>(U2, colsum, out);
}

// Round 2
// 685.288 us; speedup vs baseline: 2.5681x; 2.5681x over previous
//
#include <hip/hip_runtime.h>
#include <hip/hip_bf16.h>

#define B_  8
#define C_  1024
#define HW_ 4096
#define NK  21
#define NT  32          // HW_/128 tiles per dim

using bf16 = __hip_bfloat16;
typedef __attribute__((ext_vector_type(8))) short short8;
typedef __attribute__((ext_vector_type(4))) float float4_;

// ---------------- kernel 1: per-pixel inverse norms --------------------------
__global__ __launch_bounds__(256) void knorm(const float* __restrict__ x4, float* __restrict__ rn) {
    int t = threadIdx.x;
    int blk = blockIdx.x;              // 128 blocks: 8 b * 16 j-tiles
    int b = blk >> 4;
    int j = ((blk & 15) << 8) + t;
    const float* p = x4 + (size_t)b * C_ * HW_ + j;
    float s = 0.f;
#pragma unroll 8
    for (int c = 0; c < C_; ++c) {
        float v = p[(size_t)c * HW_];
        s = fmaf(v, v, s);
    }
    rn[b * HW_ + j] = 1.0f / fmaxf(sqrtf(s), 1e-12f);
}

// ---------------- kernel 2: transpose + scale -> XnT[b][j][c] (bf16) ---------
__global__ __launch_bounds__(256) void ktrans(const float* __restrict__ x4, const float* __restrict__ rn,
                                              bf16* __restrict__ XnT) {
    int b = blockIdx.z, ct = blockIdx.y, jt = blockIdx.x;
    int c0 = ct * 32, j0 = jt * 32;
    int tx = threadIdx.x & 31, ty = threadIdx.x >> 5;   // 32 x 8
    __shared__ float tile[32][33];
#pragma unroll
    for (int r = 0; r < 4; ++r) {
        int c = c0 + ty + r * 8;
        tile[ty + r * 8][tx] = x4[((size_t)b * C_ + c) * HW_ + j0 + tx];
    }
    __syncthreads();
#pragma unroll
    for (int r = 0; r < 4; ++r) {
        int j = j0 + ty + r * 8;
        float s = rn[b * HW_ + j];
        XnT[((size_t)b * HW_ + j) * C_ + c0 + tx] = __float2bfloat16(tile[tx][ty + r * 8] * s);
    }
}

// ---------------- kernel 3: gram + clamp + threshold + colsum + tile flags ---
// C = Xn^T Xn per batch; 128x128 tile per block, BK=64, 4 waves (2x2), each
// wave 64x64 via 4x4 frags of mfma_f32_16x16x32_bf16. Zero tiles (all entries
// < 0.5 after clamp) skip the aff store and colsum atomics entirely; a per-tile
// flag tells kprop which tiles to read.
__global__ __launch_bounds__(256) void kgram(const bf16* __restrict__ XnT, bf16* __restrict__ aff,
                                             float* __restrict__ colsum, int* __restrict__ flags) {
    int b = blockIdx.z, it = blockIdx.y, jt = blockIdx.x;
    int i0 = it * 128, j0 = jt * 128;
    int t = threadIdx.x, w = t >> 6, l = t & 63;
    int wr = w >> 1, wc = w & 1;
    int lrow = l & 15, lk = l >> 4;

    __shared__ __align__(16) bf16 As[128 * 64];
    __shared__ __align__(16) bf16 Bs[128 * 64];
    __shared__ int fl;

    const bf16* XA = XnT + ((size_t)b * HW_ + i0) * C_;
    const bf16* XB = XnT + ((size_t)b * HW_ + j0) * C_;

    float4_ acc[4][4];
#pragma unroll
    for (int m = 0; m < 4; ++m)
#pragma unroll
        for (int n = 0; n < 4; ++n) acc[m][n] = {0.f, 0.f, 0.f, 0.f};

    for (int k0 = 0; k0 < C_; k0 += 64) {
        __syncthreads();
#pragma unroll
        for (int q = 0; q < 4; ++q) {
            int m = w * 4 + q;                 // chunk 0..15, uniform per wave
            int row = m * 8 + (l >> 3);
            int col = (l & 7) * 8;
            __builtin_amdgcn_global_load_lds(
                (const __attribute__((address_space(1))) void*)(XA + (size_t)row * C_ + k0 + col),
                (__attribute__((address_space(3))) void*)(As + m * 512), 16, 0, 0);
            __builtin_amdgcn_global_load_lds(
                (const __attribute__((address_space(1))) void*)(XB + (size_t)row * C_ + k0 + col),
                (__attribute__((address_space(3))) void*)(Bs + m * 512), 16, 0, 0);
        }
        __syncthreads();
#pragma unroll
        for (int ks = 0; ks < 2; ++ks) {
            int kb = ks * 32 + lk * 8;
            short8 av[4], bv[4];
#pragma unroll
            for (int m = 0; m < 4; ++m)
                av[m] = *(const short8*)(As + (wr * 64 + m * 16 + lrow) * 64 + kb);
#pragma unroll
            for (int n = 0; n < 4; ++n)
                bv[n] = *(const short8*)(Bs + (wc * 64 + n * 16 + lrow) * 64 + kb);
#pragma unroll
            for (int m = 0; m < 4; ++m)
#pragma unroll
                for (int n = 0; n < 4; ++n)
                    acc[m][n] = __builtin_amdgcn_mfma_f32_16x16x32_bf16(av[m], bv[n], acc[m][n], 0, 0, 0);
        }
    }

    // tile nonzero flag: any raw value >= 0.5 (clamp preserves the predicate)
    bool any = false;
#pragma unroll
    for (int m = 0; m < 4; ++m)
#pragma unroll
        for (int n = 0; n < 4; ++n)
#pragma unroll
            for (int r = 0; r < 4; ++r) any |= (acc[m][n][r] >= 0.5f);

    if (t == 0) fl = 0;
    __syncthreads();
    unsigned long long bal = __ballot(any);
    if (l == 0 && bal != 0ull) atomicOr(&fl, 1);
    __syncthreads();
    if (t == 0) flags[(b * NT + it) * NT + jt] = fl;

    if (fl) {
        size_t affb = (size_t)b * HW_ * HW_;
#pragma unroll
        for (int n = 0; n < 4; ++n) {
            int j = j0 + wc * 64 + n * 16 + lrow;
            float cs = 0.f;
#pragma unroll
            for (int m = 0; m < 4; ++m) {
#pragma unroll
                for (int r = 0; r < 4; ++r) {
                    float v = acc[m][n][r];
                    v = fminf(fmaxf(v, 0.01f), 0.999f);
                    v = (v < 0.5f) ? 0.0f : v;
                    bf16 bb = __float2bfloat16(v);
                    int i = i0 + wr * 64 + m * 16 + lk * 4 + r;
                    aff[affb + (size_t)i * HW_ + j] = bb;
                    cs += __bfloat162float(bb);
                }
            }
            cs += __shfl_xor(cs, 16);
            cs += __shfl_xor(cs, 32);
            if (lk == 0) atomicAdd(&colsum[b * HW_ + j], cs);
        }
    }
}

// ---------------- kernel 4: out[k][j] = (sum_i lf[k][i]*aff[i][j]) / colsum[j]
// One thread owns one column j; skips whole 128x128 tiles via flags.
__global__ __launch_bounds__(128) void kprop(const float* __restrict__ lf, const bf16* __restrict__ aff,
                                             const int* __restrict__ flags, const float* __restrict__ colsum,
                                             float* __restrict__ outp) {
    int b = blockIdx.y, jt = blockIdx.x;
    int t = threadIdx.x;                 // 128 threads
    int j = jt * 128 + t;
    __shared__ float lfs[NK * 128];
    float acc[NK];
#pragma unroll
    for (int k = 0; k < NK; ++k) acc[k] = 0.f;

    for (int it = 0; it < NT; ++it) {
        if (flags[(b * NT + it) * NT + jt] == 0) continue;   // block-uniform branch
        __syncthreads();
        for (int idx = t; idx < NK * 128; idx += 128)
            lfs[idx] = lf[((size_t)b * NK + (idx >> 7)) * HW_ + it * 128 + (idx & 127)];
        __syncthreads();
        const bf16* ap = aff + ((size_t)b * HW_ + it * 128) * HW_ + j;
        for (int ii = 0; ii < 128; ++ii) {
            float a = __bfloat162float(ap[(size_t)ii * HW_]);
#pragma unroll
            for (int k = 0; k < NK; ++k)
                acc[k] = fmaf(lfs[(k << 7) + ii], a, acc[k]);
        }
    }
    float inv = 1.0f / colsum[b * HW_ + j];
#pragma unroll
    for (int k = 0; k < NK; ++k)
        outp[((size_t)b * NK + k) * HW_ + j] = acc[k] * inv;
}

extern "C" void kernel_launch(void* const* d_in, const int* in_sizes, int n_in,
                              void* d_out, int out_size, void* d_ws, size_t ws_size,
                              hipStream_t stream) {
    const float* x4 = (const float*)d_in[0];
    const float* logits = (const float*)d_in[1];
    float* out = (float*)d_out;

    char* w = (char*)d_ws;
    size_t off = 0;
    auto take = [&](size_t bytes) {
        char* p = w + off;
        off += (bytes + 255) & ~(size_t)255;
        return p;
    };
    bf16* XnT     = (bf16*)take((size_t)B_ * HW_ * C_ * 2);     //  64 MiB
    bf16* aff     = (bf16*)take((size_t)B_ * HW_ * HW_ * 2);    // 256 MiB
    float* rn     = (float*)take((size_t)B_ * HW_ * 4);
    float* colsum = (float*)take((size_t)B_ * HW_ * 4);         // adjacent to flags
    int*   flags  = (int*)take((size_t)B_ * NT * NT * 4);
    float* lf1    = (float*)take((size_t)B_ * NK * HW_ * 4);

    // zero colsum + flags in one shot (they are adjacent, 256B-aligned blocks)
    hipMemsetAsync(colsum, 0, (size_t)B_ * HW_ * 4 + 256 + (size_t)B_ * NT * NT * 4, stream);

    knorm <<<dim3(128), dim3(256), 0, stream>>>(x4, rn);
    ktrans<<<dim3(HW_ / 32, C_ / 32, B_), dim3(256), 0, stream>>>(x4, rn, XnT);
    kgram <<<dim3(NT, NT, B_), dim3(256), 0, stream>>>(XnT, aff, colsum, flags);

    // pcm = 2 propagation rounds, colsum division fused into kprop epilogue
    kprop<<<dim3(NT, B_), dim3(128), 0, stream>>>(logits, aff, flags, colsum, lf1);
    kprop<<<dim3(NT, B_), dim3(128), 0, stream>>>(lf1, aff, flags, colsum, out);
}

// Round 3
// 610.106 us; speedup vs baseline: 2.8846x; 1.1232x over previous
//
#include <hip/hip_runtime.h>
#include <hip/hip_bf16.h>

#define B_  8
#define C_  1024
#define HW_ 4096
#define NK  21
#define NT  32          // HW_/128 tiles per dim

using bf16 = __hip_bfloat16;
typedef __attribute__((ext_vector_type(8))) short short8;
typedef __attribute__((ext_vector_type(4))) float float4_;

// ---------------- kernel 1: per-pixel inverse norms --------------------------
__global__ __launch_bounds__(256) void knorm(const float* __restrict__ x4, float* __restrict__ rn) {
    int t = threadIdx.x;
    int blk = blockIdx.x;              // 128 blocks: 8 b * 16 j-tiles
    int b = blk >> 4;
    int j = ((blk & 15) << 8) + t;
    const float* p = x4 + (size_t)b * C_ * HW_ + j;
    float s = 0.f;
#pragma unroll 8
    for (int c = 0; c < C_; ++c) {
        float v = p[(size_t)c * HW_];
        s = fmaf(v, v, s);
    }
    rn[b * HW_ + j] = 1.0f / fmaxf(sqrtf(s), 1e-12f);
}

// ---------------- kernel 2: transpose + scale -> XnT[b][j][c] (bf16) ---------
__global__ __launch_bounds__(256) void ktrans(const float* __restrict__ x4, const float* __restrict__ rn,
                                              bf16* __restrict__ XnT) {
    int b = blockIdx.z, ct = blockIdx.y, jt = blockIdx.x;
    int c0 = ct * 32, j0 = jt * 32;
    int tx = threadIdx.x & 31, ty = threadIdx.x >> 5;   // 32 x 8
    __shared__ float tile[32][33];
#pragma unroll
    for (int r = 0; r < 4; ++r) {
        int c = c0 + ty + r * 8;
        tile[ty + r * 8][tx] = x4[((size_t)b * C_ + c) * HW_ + j0 + tx];
    }
    __syncthreads();
#pragma unroll
    for (int r = 0; r < 4; ++r) {
        int j = j0 + ty + r * 8;
        float s = rn[b * HW_ + j];
        XnT[((size_t)b * HW_ + j) * C_ + c0 + tx] = __float2bfloat16(tile[tx][ty + r * 8] * s);
    }
}

// ---------------- kernel 3: gram + clamp + threshold + colsum + tile flags ---
// C = Xn^T Xn per batch; 128x128 tile per block, BK=64, 4 waves (2x2), each
// wave 64x64 via 4x4 frags of mfma_f32_16x16x32_bf16.
// LDS layout is XOR-swizzled in 8-element (16B) chunks: row r slot p holds
// global k-chunk (p ^ (r&7)). This kills the 16-way bank conflict of the
// unswizzled 128B-row layout (stride 128B == 32 banks).
__global__ __launch_bounds__(256) void kgram(const bf16* __restrict__ XnT, bf16* __restrict__ aff,
                                             float* __restrict__ colsum, int* __restrict__ flags) {
    int b = blockIdx.z, it = blockIdx.y, jt = blockIdx.x;
    int i0 = it * 128, j0 = jt * 128;
    int t = threadIdx.x, w = t >> 6, l = t & 63;
    int wr = w >> 1, wc = w & 1;
    int lrow = l & 15, lk = l >> 4;

    __shared__ __align__(16) bf16 As[128 * 64];
    __shared__ __align__(16) bf16 Bs[128 * 64];
    __shared__ int fl;

    const bf16* XA = XnT + ((size_t)b * HW_ + i0) * C_;
    const bf16* XB = XnT + ((size_t)b * HW_ + j0) * C_;

    // staging: lane l covers row (l>>3) of its 8-row group; fetches global
    // chunk ((l&7) ^ (l>>3)) so LDS slot (l&7) holds chunk (slot ^ (row&7)).
    int srow = l >> 3;
    int scol = ((l & 7) ^ srow) * 8;

    float4_ acc[4][4];
#pragma unroll
    for (int m = 0; m < 4; ++m)
#pragma unroll
        for (int n = 0; n < 4; ++n) acc[m][n] = {0.f, 0.f, 0.f, 0.f};

    for (int k0 = 0; k0 < C_; k0 += 64) {
        __syncthreads();
#pragma unroll
        for (int q = 0; q < 4; ++q) {
            int m = w * 4 + q;                 // chunk 0..15, uniform per wave
            int row = m * 8 + srow;
            __builtin_amdgcn_global_load_lds(
                (const __attribute__((address_space(1))) void*)(XA + (size_t)row * C_ + k0 + scol),
                (__attribute__((address_space(3))) void*)(As + m * 512), 16, 0, 0);
            __builtin_amdgcn_global_load_lds(
                (const __attribute__((address_space(1))) void*)(XB + (size_t)row * C_ + k0 + scol),
                (__attribute__((address_space(3))) void*)(Bs + m * 512), 16, 0, 0);
        }
        __syncthreads();
#pragma unroll
        for (int ks = 0; ks < 2; ++ks) {
            int c = ks * 4 + lk;               // k-chunk index 0..7
            short8 av[4], bv[4];
#pragma unroll
            for (int m = 0; m < 4; ++m) {
                int r = wr * 64 + m * 16 + lrow;
                av[m] = *(const short8*)(As + r * 64 + (c ^ (r & 7)) * 8);
            }
#pragma unroll
            for (int n = 0; n < 4; ++n) {
                int r = wc * 64 + n * 16 + lrow;
                bv[n] = *(const short8*)(Bs + r * 64 + (c ^ (r & 7)) * 8);
            }
#pragma unroll
            for (int m = 0; m < 4; ++m)
#pragma unroll
                for (int n = 0; n < 4; ++n)
                    acc[m][n] = __builtin_amdgcn_mfma_f32_16x16x32_bf16(av[m], bv[n], acc[m][n], 0, 0, 0);
        }
    }

    // tile nonzero flag: any raw value >= 0.5 (clamp preserves the predicate)
    bool any = false;
#pragma unroll
    for (int m = 0; m < 4; ++m)
#pragma unroll
        for (int n = 0; n < 4; ++n)
#pragma unroll
            for (int r = 0; r < 4; ++r) any |= (acc[m][n][r] >= 0.5f);

    if (t == 0) fl = 0;
    __syncthreads();
    unsigned long long bal = __ballot(any);
    if (l == 0 && bal != 0ull) atomicOr(&fl, 1);
    __syncthreads();
    if (t == 0) flags[(b * NT + it) * NT + jt] = fl;

    if (fl) {
        size_t affb = (size_t)b * HW_ * HW_;
#pragma unroll
        for (int n = 0; n < 4; ++n) {
            int j = j0 + wc * 64 + n * 16 + lrow;
            float cs = 0.f;
#pragma unroll
            for (int m = 0; m < 4; ++m) {
#pragma unroll
                for (int r = 0; r < 4; ++r) {
                    float v = acc[m][n][r];
                    v = fminf(fmaxf(v, 0.01f), 0.999f);
                    v = (v < 0.5f) ? 0.0f : v;
                    bf16 bb = __float2bfloat16(v);
                    int i = i0 + wr * 64 + m * 16 + lk * 4 + r;
                    aff[affb + (size_t)i * HW_ + j] = bb;
                    cs += __bfloat162float(bb);
                }
            }
            cs += __shfl_xor(cs, 16);
            cs += __shfl_xor(cs, 32);
            if (lk == 0) atomicAdd(&colsum[b * HW_ + j], cs);
        }
    }
}

// ---------------- kernel 4: out[k][j] = (sum_i lf[k][i]*aff[i][j]) / colsum[j]
// One thread owns one column j; skips whole 128x128 tiles via flags.
__global__ __launch_bounds__(128) void kprop(const float* __restrict__ lf, const bf16* __restrict__ aff,
                                             const int* __restrict__ flags, const float* __restrict__ colsum,
                                             float* __restrict__ outp) {
    int b = blockIdx.y, jt = blockIdx.x;
    int t = threadIdx.x;                 // 128 threads
    int j = jt * 128 + t;
    __shared__ float lfs[NK * 128];
    float acc[NK];
#pragma unroll
    for (int k = 0; k < NK; ++k) acc[k] = 0.f;

    for (int it = 0; it < NT; ++it) {
        if (flags[(b * NT + it) * NT + jt] == 0) continue;   // block-uniform branch
        __syncthreads();
        for (int idx = t; idx < NK * 128; idx += 128)
            lfs[idx] = lf[((size_t)b * NK + (idx >> 7)) * HW_ + it * 128 + (idx & 127)];
        __syncthreads();
        const bf16* ap = aff + ((size_t)b * HW_ + it * 128) * HW_ + j;
        for (int ii = 0; ii < 128; ++ii) {
            float a = __bfloat162float(ap[(size_t)ii * HW_]);
#pragma unroll
            for (int k = 0; k < NK; ++k)
                acc[k] = fmaf(lfs[(k << 7) + ii], a, acc[k]);
        }
    }
    float inv = 1.0f / colsum[b * HW_ + j];
#pragma unroll
    for (int k = 0; k < NK; ++k)
        outp[((size_t)b * NK + k) * HW_ + j] = acc[k] * inv;
}

extern "C" void kernel_launch(void* const* d_in, const int* in_sizes, int n_in,
                              void* d_out, int out_size, void* d_ws, size_t ws_size,
                              hipStream_t stream) {
    const float* x4 = (const float*)d_in[0];
    const float* logits = (const float*)d_in[1];
    float* out = (float*)d_out;

    char* w = (char*)d_ws;
    size_t off = 0;
    auto take = [&](size_t bytes) {
        char* p = w + off;
        off += (bytes + 255) & ~(size_t)255;
        return p;
    };
    bf16* XnT     = (bf16*)take((size_t)B_ * HW_ * C_ * 2);     //  64 MiB
    bf16* aff     = (bf16*)take((size_t)B_ * HW_ * HW_ * 2);    // 256 MiB
    float* rn     = (float*)take((size_t)B_ * HW_ * 4);
    float* colsum = (float*)take((size_t)B_ * HW_ * 4);         // adjacent to flags
    int*   flags  = (int*)take((size_t)B_ * NT * NT * 4);
    float* lf1    = (float*)take((size_t)B_ * NK * HW_ * 4);

    // zero colsum + flags in one shot (they are adjacent, 256B-aligned blocks)
    hipMemsetAsync(colsum, 0, (size_t)B_ * HW_ * 4 + 256 + (size_t)B_ * NT * NT * 4, stream);

    knorm <<<dim3(128), dim3(256), 0, stream>>>(x4, rn);
    ktrans<<<dim3(HW_ / 32, C_ / 32, B_), dim3(256), 0, stream>>>(x4, rn, XnT);
    kgram <<<dim3(NT, NT, B_), dim3(256), 0, stream>>>(XnT, aff, colsum, flags);

    // pcm = 2 propagation rounds, colsum division fused into kprop epilogue
    kprop<<<dim3(NT, B_), dim3(128), 0, stream>>>(logits, aff, flags, colsum, lf1);
    kprop<<<dim3(NT, B_), dim3(128), 0, stream>>>(lf1, aff, flags, colsum, out);
}

// Round 4
// 452.152 us; speedup vs baseline: 3.8923x; 1.3493x over previous
//
#include <hip/hip_runtime.h>
#include <hip/hip_bf16.h>

#define B_  8
#define C_  1024
#define HW_ 4096
#define NK  21
#define NT  32          // HW_/128 tiles per dim
#define NTRI (NT * (NT + 1) / 2)   // 528 upper-triangle tiles

using bf16 = __hip_bfloat16;
typedef __attribute__((ext_vector_type(8))) short short8;
typedef __attribute__((ext_vector_type(4))) float float4_;

// ---------------- kernel 1a: partial sum-of-squares (split over C) -----------
__global__ __launch_bounds__(256) void knorm1(const float* __restrict__ x4, float* __restrict__ sumsq) {
    int t = threadIdx.x;
    int b = blockIdx.z;
    int c0 = blockIdx.y * 128;
    int j = blockIdx.x * 256 + t;
    const float* p = x4 + ((size_t)b * C_ + c0) * HW_ + j;
    float s = 0.f;
#pragma unroll 8
    for (int c = 0; c < 128; ++c) {
        float v = p[(size_t)c * HW_];
        s = fmaf(v, v, s);
    }
    atomicAdd(&sumsq[b * HW_ + j], s);
}

// ---------------- kernel 1b: finalize inverse norms --------------------------
__global__ __launch_bounds__(256) void knorm2(const float* __restrict__ sumsq, float* __restrict__ rn) {
    int idx = blockIdx.x * 256 + threadIdx.x;
    rn[idx] = 1.0f / fmaxf(sqrtf(sumsq[idx]), 1e-12f);
}

// ---------------- kernel 2: transpose + scale -> XnT[b][j][c] (bf16) ---------
__global__ __launch_bounds__(256) void ktrans(const float* __restrict__ x4, const float* __restrict__ rn,
                                              bf16* __restrict__ XnT) {
    int b = blockIdx.z, ct = blockIdx.y, jt = blockIdx.x;
    int c0 = ct * 32, j0 = jt * 32;
    int tx = threadIdx.x & 31, ty = threadIdx.x >> 5;   // 32 x 8
    __shared__ float tile[32][33];
#pragma unroll
    for (int r = 0; r < 4; ++r) {
        int c = c0 + ty + r * 8;
        tile[ty + r * 8][tx] = x4[((size_t)b * C_ + c) * HW_ + j0 + tx];
    }
    __syncthreads();
#pragma unroll
    for (int r = 0; r < 4; ++r) {
        int j = j0 + ty + r * 8;
        float s = rn[b * HW_ + j];
        XnT[((size_t)b * HW_ + j) * C_ + c0 + tx] = __float2bfloat16(tile[tx][ty + r * 8] * s);
    }
}

// ---------------- kernel 3: symmetric gram, upper-triangle tiles only --------
// 128x128 tile per block, BK=64, 4 waves (2x2), 4x4 frags of
// mfma_f32_16x16x32_bf16, XOR-swizzled LDS (conflict-free). Off-diagonal
// nonzero tiles mirror their store to (j,i) and add row sums to colsum.
__global__ __launch_bounds__(256) void kgram(const bf16* __restrict__ XnT, bf16* __restrict__ aff,
                                             float* __restrict__ colsum, int* __restrict__ flags) {
    int b = blockIdx.y;
    // triangular decode: p -> (it, jt), it <= jt, row-major upper triangle
    int p = blockIdx.x;
    int it = (int)((2.0f * NT + 1.0f - sqrtf((2.0f * NT + 1.0f) * (2.0f * NT + 1.0f) - 8.0f * (float)p)) * 0.5f);
    while (it > 0 && p < it * NT - it * (it - 1) / 2) --it;
    while (p >= (it + 1) * NT - (it + 1) * it / 2) ++it;
    int jt = it + p - (it * NT - it * (it - 1) / 2);

    int i0 = it * 128, j0 = jt * 128;
    int t = threadIdx.x, w = t >> 6, l = t & 63;
    int wr = w >> 1, wc = w & 1;
    int lrow = l & 15, lk = l >> 4;

    __shared__ __align__(16) bf16 As[128 * 64];
    __shared__ __align__(16) bf16 Bs[128 * 64];
    __shared__ int fl;

    const bf16* XA = XnT + ((size_t)b * HW_ + i0) * C_;
    const bf16* XB = XnT + ((size_t)b * HW_ + j0) * C_;

    int srow = l >> 3;
    int scol = ((l & 7) ^ srow) * 8;

    float4_ acc[4][4];
#pragma unroll
    for (int m = 0; m < 4; ++m)
#pragma unroll
        for (int n = 0; n < 4; ++n) acc[m][n] = {0.f, 0.f, 0.f, 0.f};

    for (int k0 = 0; k0 < C_; k0 += 64) {
        __syncthreads();
#pragma unroll
        for (int q = 0; q < 4; ++q) {
            int m = w * 4 + q;                 // chunk 0..15, uniform per wave
            int row = m * 8 + srow;
            __builtin_amdgcn_global_load_lds(
                (const __attribute__((address_space(1))) void*)(XA + (size_t)row * C_ + k0 + scol),
                (__attribute__((address_space(3))) void*)(As + m * 512), 16, 0, 0);
            __builtin_amdgcn_global_load_lds(
                (const __attribute__((address_space(1))) void*)(XB + (size_t)row * C_ + k0 + scol),
                (__attribute__((address_space(3))) void*)(Bs + m * 512), 16, 0, 0);
        }
        __syncthreads();
#pragma unroll
        for (int ks = 0; ks < 2; ++ks) {
            int c = ks * 4 + lk;               // k-chunk index 0..7
            short8 av[4], bv[4];
#pragma unroll
            for (int m = 0; m < 4; ++m) {
                int r = wr * 64 + m * 16 + lrow;
                av[m] = *(const short8*)(As + r * 64 + (c ^ (r & 7)) * 8);
            }
#pragma unroll
            for (int n = 0; n < 4; ++n) {
                int r = wc * 64 + n * 16 + lrow;
                bv[n] = *(const short8*)(Bs + r * 64 + (c ^ (r & 7)) * 8);
            }
#pragma unroll
            for (int m = 0; m < 4; ++m)
#pragma unroll
                for (int n = 0; n < 4; ++n)
                    acc[m][n] = __builtin_amdgcn_mfma_f32_16x16x32_bf16(av[m], bv[n], acc[m][n], 0, 0, 0);
        }
    }

    // tile nonzero flag: any raw value >= 0.5 (clamp preserves the predicate)
    bool any = false;
#pragma unroll
    for (int m = 0; m < 4; ++m)
#pragma unroll
        for (int n = 0; n < 4; ++n)
#pragma unroll
            for (int r = 0; r < 4; ++r) any |= (acc[m][n][r] >= 0.5f);

    if (t == 0) fl = 0;
    __syncthreads();
    unsigned long long bal = __ballot(any);
    if (l == 0 && bal != 0ull) atomicOr(&fl, 1);
    __syncthreads();
    bool mirror = (it != jt);
    if (t == 0) {
        flags[(b * NT + it) * NT + jt] = fl;
        if (mirror) flags[(b * NT + jt) * NT + it] = fl;
    }

    if (fl) {
        size_t affb = (size_t)b * HW_ * HW_;
        float rsum[4][4];
#pragma unroll
        for (int m = 0; m < 4; ++m)
#pragma unroll
            for (int r = 0; r < 4; ++r) rsum[m][r] = 0.f;

#pragma unroll
        for (int n = 0; n < 4; ++n) {
            int j = j0 + wc * 64 + n * 16 + lrow;
            float cs = 0.f;
#pragma unroll
            for (int m = 0; m < 4; ++m) {
#pragma unroll
                for (int r = 0; r < 4; ++r) {
                    float v = acc[m][n][r];
                    v = fminf(fmaxf(v, 0.01f), 0.999f);
                    v = (v < 0.5f) ? 0.0f : v;
                    bf16 bb = __float2bfloat16(v);
                    int i = i0 + wr * 64 + m * 16 + lk * 4 + r;
                    aff[affb + (size_t)i * HW_ + j] = bb;
                    float bf = __bfloat162float(bb);
                    cs += bf;
                    rsum[m][r] += bf;
                    if (mirror) aff[affb + (size_t)j * HW_ + i] = bb;
                }
            }
            cs += __shfl_xor(cs, 16);
            cs += __shfl_xor(cs, 32);
            if (lk == 0) atomicAdd(&colsum[b * HW_ + j], cs);
        }
        if (mirror) {
            // mirrored tile's column sums = this tile's row sums
#pragma unroll
            for (int m = 0; m < 4; ++m) {
#pragma unroll
                for (int r = 0; r < 4; ++r) {
                    float s = rsum[m][r];
                    s += __shfl_xor(s, 1);
                    s += __shfl_xor(s, 2);
                    s += __shfl_xor(s, 4);
                    s += __shfl_xor(s, 8);
                    if (lrow == 0) {
                        int i = i0 + wr * 64 + m * 16 + lk * 4 + r;
                        atomicAdd(&colsum[b * HW_ + i], s);
                    }
                }
            }
        }
    }
}

// ---------------- kernel 4: out[k][j] = (sum_i lf[k][i]*aff[i][j]) / colsum[j]
__global__ __launch_bounds__(128) void kprop(const float* __restrict__ lf, const bf16* __restrict__ aff,
                                             const int* __restrict__ flags, const float* __restrict__ colsum,
                                             float* __restrict__ outp) {
    int b = blockIdx.y, jt = blockIdx.x;
    int t = threadIdx.x;                 // 128 threads
    int j = jt * 128 + t;
    __shared__ float lfs[NK * 128];
    float acc[NK];
#pragma unroll
    for (int k = 0; k < NK; ++k) acc[k] = 0.f;

    for (int it = 0; it < NT; ++it) {
        if (flags[(b * NT + it) * NT + jt] == 0) continue;   // block-uniform branch
        __syncthreads();
        for (int idx = t; idx < NK * 128; idx += 128)
            lfs[idx] = lf[((size_t)b * NK + (idx >> 7)) * HW_ + it * 128 + (idx & 127)];
        __syncthreads();
        const bf16* ap = aff + ((size_t)b * HW_ + it * 128) * HW_ + j;
        for (int ii = 0; ii < 128; ++ii) {
            float a = __bfloat162float(ap[(size_t)ii * HW_]);
#pragma unroll
            for (int k = 0; k < NK; ++k)
                acc[k] = fmaf(lfs[(k << 7) + ii], a, acc[k]);
        }
    }
    float inv = 1.0f / colsum[b * HW_ + j];
#pragma unroll
    for (int k = 0; k < NK; ++k)
        outp[((size_t)b * NK + k) * HW_ + j] = acc[k] * inv;
}

extern "C" void kernel_launch(void* const* d_in, const int* in_sizes, int n_in,
                              void* d_out, int out_size, void* d_ws, size_t ws_size,
                              hipStream_t stream) {
    const float* x4 = (const float*)d_in[0];
    const float* logits = (const float*)d_in[1];
    float* out = (float*)d_out;

    char* w = (char*)d_ws;
    size_t off = 0;
    auto take = [&](size_t bytes) {
        char* p = w + off;
        off += (bytes + 255) & ~(size_t)255;
        return p;
    };
    bf16* XnT     = (bf16*)take((size_t)B_ * HW_ * C_ * 2);     //  64 MiB
    bf16* aff     = (bf16*)take((size_t)B_ * HW_ * HW_ * 2);    // 256 MiB
    float* rn     = (float*)take((size_t)B_ * HW_ * 4);
    // colsum, flags, sumsq contiguous (each a multiple of 256B) -> one memset
    float* colsum = (float*)take((size_t)B_ * HW_ * 4);
    int*   flags  = (int*)take((size_t)B_ * NT * NT * 4);
    float* sumsq  = (float*)take((size_t)B_ * HW_ * 4);
    float* lf1    = (float*)take((size_t)B_ * NK * HW_ * 4);

    hipMemsetAsync(colsum, 0, (size_t)B_ * HW_ * 4 + (size_t)B_ * NT * NT * 4 + (size_t)B_ * HW_ * 4, stream);

    knorm1<<<dim3(HW_ / 256, 8, B_), dim3(256), 0, stream>>>(x4, sumsq);
    knorm2<<<dim3(B_ * HW_ / 256), dim3(256), 0, stream>>>(sumsq, rn);
    ktrans<<<dim3(HW_ / 32, C_ / 32, B_), dim3(256), 0, stream>>>(x4, rn, XnT);
    kgram <<<dim3(NTRI, B_), dim3(256), 0, stream>>>(XnT, aff, colsum, flags);

    // pcm = 2 propagation rounds, colsum division fused into kprop epilogue
    kprop<<<dim3(NT, B_), dim3(128), 0, stream>>>(logits, aff, flags, colsum, lf1);
    kprop<<<dim3(NT, B_), dim3(128), 0, stream>>>(lf1, aff, flags, colsum, out);
}

// Round 5
// 395.422 us; speedup vs baseline: 4.4507x; 1.1435x over previous
//
#include <hip/hip_runtime.h>
#include <hip/hip_bf16.h>

#define B_  8
#define C_  1024
#define HW_ 4096
#define NK  21
#define NT  32          // HW_/128 tiles per dim
#define NTRI (NT * (NT + 1) / 2)   // 528 upper-triangle tiles

using bf16 = __hip_bfloat16;
typedef __attribute__((ext_vector_type(4))) float float4_;

// ---------------- kernel 1: partial sum-of-squares (split over C) ------------
__global__ __launch_bounds__(256) void knorm1(const float* __restrict__ x4, float* __restrict__ sumsq) {
    int t = threadIdx.x;
    int b = blockIdx.z;
    int c0 = blockIdx.y * 128;
    int j = blockIdx.x * 256 + t;
    const float* p = x4 + ((size_t)b * C_ + c0) * HW_ + j;
    float s = 0.f;
#pragma unroll 8
    for (int c = 0; c < 128; ++c) {
        float v = p[(size_t)c * HW_];
        s = fmaf(v, v, s);
    }
    atomicAdd(&sumsq[b * HW_ + j], s);
}

// ---------------- kernel 2: transpose + normalize -> Xn8[b][j][c] (fp8 e4m3) -
// 64j x 64c tile; phase1 coalesced fp32 loads into LDS; phase2 each thread
// emits 16 fp8 bytes of one row (16B vectorized store). rsqrt folded in.
__global__ __launch_bounds__(256) void ktrans(const float* __restrict__ x4, const float* __restrict__ sumsq,
                                              unsigned char* __restrict__ Xn8) {
    int b = blockIdx.z, ct = blockIdx.y, jt = blockIdx.x;
    int c0 = ct * 64, j0 = jt * 64;
    int t = threadIdx.x;
    __shared__ float tile[64][65];

    int jl = t & 63, cl = t >> 6;
#pragma unroll
    for (int cc = 0; cc < 16; ++cc) {
        int c = cc * 4 + cl;
        tile[c][jl] = x4[((size_t)b * C_ + c0 + c) * HW_ + j0 + jl];
    }
    __syncthreads();

    int j = t >> 2, cb = (t & 3) * 16;
    int jg = j0 + j;
    float inv = 1.0f / fmaxf(sqrtf(sumsq[b * HW_ + jg]), 1e-12f);

    unsigned int pk[4];
#pragma unroll
    for (int q = 0; q < 4; ++q) {
        float f0 = tile[cb + q * 4 + 0][j] * inv;
        float f1 = tile[cb + q * 4 + 1][j] * inv;
        float f2 = tile[cb + q * 4 + 2][j] * inv;
        float f3 = tile[cb + q * 4 + 3][j] * inv;
        unsigned int r = 0;
        r = __builtin_amdgcn_cvt_pk_fp8_f32(f0, f1, r, false);
        r = __builtin_amdgcn_cvt_pk_fp8_f32(f2, f3, r, true);
        pk[q] = r;
    }
    uint4 v = make_uint4(pk[0], pk[1], pk[2], pk[3]);
    *(uint4*)(Xn8 + ((size_t)b * HW_ + jg) * C_ + c0 + cb) = v;
}

// ---------------- kernel 3: symmetric gram (fp8 MFMA), upper-triangle tiles --
// 128x128 tile per block, BK=128 fp8 (16KB+16KB LDS), 4 waves (2x2), 4x4 frags
// of mfma_f32_16x16x32_fp8_fp8 (i64 operands, ds_read_b64).
// LDS XOR-swizzled at 16B granularity: row r slot s holds global 16B-chunk
// s ^ ((r>>1)&7) -> frag reads are bank-conflict-free.
__global__ __launch_bounds__(256) void kgram(const unsigned char* __restrict__ Xn8, bf16* __restrict__ aff,
                                             float* __restrict__ colsum, int* __restrict__ flags) {
    int b = blockIdx.y;
    int p = blockIdx.x;
    int it = (int)((2.0f * NT + 1.0f - sqrtf((2.0f * NT + 1.0f) * (2.0f * NT + 1.0f) - 8.0f * (float)p)) * 0.5f);
    while (it > 0 && p < it * NT - it * (it - 1) / 2) --it;
    while (p >= (it + 1) * NT - (it + 1) * it / 2) ++it;
    int jt = it + p - (it * NT - it * (it - 1) / 2);

    int i0 = it * 128, j0 = jt * 128;
    int t = threadIdx.x, w = t >> 6, l = t & 63;
    int wr = w >> 1, wc = w & 1;
    int lrow = l & 15, lk = l >> 4;

    __shared__ __align__(16) unsigned char As[128 * 128];
    __shared__ __align__(16) unsigned char Bs[128 * 128];
    __shared__ int fl;

    const unsigned char* XA = Xn8 + ((size_t)b * HW_ + i0) * C_;
    const unsigned char* XB = Xn8 + ((size_t)b * HW_ + j0) * C_;

    // staging geometry: each issue covers 8 rows x 128B; lane l -> row off l>>3,
    // LDS slot s = l&7; fetch global chunk s ^ ((R>>1)&7).
    int srow = l >> 3;
    int sslot = l & 7;

    float4_ acc[4][4];
#pragma unroll
    for (int m = 0; m < 4; ++m)
#pragma unroll
        for (int n = 0; n < 4; ++n) acc[m][n] = {0.f, 0.f, 0.f, 0.f};

    // per-lane constant slot offsets for frag reads: row-dependent part is
    // swz = (lrow>>1)&7 (tile row base is a multiple of 16)
    int swz = (lrow >> 1) & 7;

    for (int k0 = 0; k0 < C_; k0 += 128) {
        __syncthreads();
#pragma unroll
        for (int q = 0; q < 4; ++q) {
            int R = (w * 4 + q) * 8 + srow;           // 0..127
            int gp = sslot ^ ((R >> 1) & 7);
            __builtin_amdgcn_global_load_lds(
                (const __attribute__((address_space(1))) void*)(XA + (size_t)R * C_ + k0 + gp * 16),
                (__attribute__((address_space(3))) void*)(As + R * 128 + sslot * 16), 16, 0, 0);
            __builtin_amdgcn_global_load_lds(
                (const __attribute__((address_space(1))) void*)(XB + (size_t)R * C_ + k0 + gp * 16),
                (__attribute__((address_space(3))) void*)(Bs + R * 128 + sslot * 16), 16, 0, 0);
        }
        __syncthreads();
#pragma unroll
        for (int ks = 0; ks < 4; ++ks) {
            int cc = ks * 4 + lk;                      // 8B-granule index 0..15
            int off = ((cc >> 1) ^ swz) * 16 + (cc & 1) * 8;
            long av[4], bv[4];
#pragma unroll
            for (int m = 0; m < 4; ++m) {
                int r = wr * 64 + m * 16 + lrow;
                av[m] = *(const long*)(As + r * 128 + off);
            }
#pragma unroll
            for (int n = 0; n < 4; ++n) {
                int r = wc * 64 + n * 16 + lrow;
                bv[n] = *(const long*)(Bs + r * 128 + off);
            }
#pragma unroll
            for (int m = 0; m < 4; ++m)
#pragma unroll
                for (int n = 0; n < 4; ++n)
                    acc[m][n] = __builtin_amdgcn_mfma_f32_16x16x32_fp8_fp8(av[m], bv[n], acc[m][n], 0, 0, 0);
        }
    }

    // tile nonzero flag: any raw value >= 0.5
    bool any = false;
#pragma unroll
    for (int m = 0; m < 4; ++m)
#pragma unroll
        for (int n = 0; n < 4; ++n)
#pragma unroll
            for (int r = 0; r < 4; ++r) any |= (acc[m][n][r] >= 0.5f);

    if (t == 0) fl = 0;
    __syncthreads();
    unsigned long long bal = __ballot(any);
    if (l == 0 && bal != 0ull) atomicOr(&fl, 1);
    __syncthreads();
    bool mirror = (it != jt);
    if (t == 0) {
        flags[(b * NT + it) * NT + jt] = fl;
        if (mirror) flags[(b * NT + jt) * NT + it] = fl;
    }

    if (fl) {
        size_t affb = (size_t)b * HW_ * HW_;
        float rsum[4][4];
#pragma unroll
        for (int m = 0; m < 4; ++m)
#pragma unroll
            for (int r = 0; r < 4; ++r) rsum[m][r] = 0.f;

#pragma unroll
        for (int n = 0; n < 4; ++n) {
            int j = j0 + wc * 64 + n * 16 + lrow;
            float cs = 0.f;
#pragma unroll
            for (int m = 0; m < 4; ++m) {
#pragma unroll
                for (int r = 0; r < 4; ++r) {
                    float v = acc[m][n][r];
                    v = fminf(fmaxf(v, 0.01f), 0.999f);
                    v = (v < 0.5f) ? 0.0f : v;
                    bf16 bb = __float2bfloat16(v);
                    int i = i0 + wr * 64 + m * 16 + lk * 4 + r;
                    aff[affb + (size_t)i * HW_ + j] = bb;
                    float bf = __bfloat162float(bb);
                    cs += bf;
                    rsum[m][r] += bf;
                    if (mirror) aff[affb + (size_t)j * HW_ + i] = bb;
                }
            }
            cs += __shfl_xor(cs, 16);
            cs += __shfl_xor(cs, 32);
            if (lk == 0) atomicAdd(&colsum[b * HW_ + j], cs);
        }
        if (mirror) {
#pragma unroll
            for (int m = 0; m < 4; ++m) {
#pragma unroll
                for (int r = 0; r < 4; ++r) {
                    float s = rsum[m][r];
                    s += __shfl_xor(s, 1);
                    s += __shfl_xor(s, 2);
                    s += __shfl_xor(s, 4);
                    s += __shfl_xor(s, 8);
                    if (lrow == 0) {
                        int i = i0 + wr * 64 + m * 16 + lk * 4 + r;
                        atomicAdd(&colsum[b * HW_ + i], s);
                    }
                }
            }
        }
    }
}

// ---------------- kernel 4: out[k][j] = (sum_i lf[k][i]*aff[i][j]) / colsum[j]
__global__ __launch_bounds__(128) void kprop(const float* __restrict__ lf, const bf16* __restrict__ aff,
                                             const int* __restrict__ flags, const float* __restrict__ colsum,
                                             float* __restrict__ outp) {
    int b = blockIdx.y, jt = blockIdx.x;
    int t = threadIdx.x;                 // 128 threads
    int j = jt * 128 + t;
    __shared__ float lfs[NK * 128];
    float acc[NK];
#pragma unroll
    for (int k = 0; k < NK; ++k) acc[k] = 0.f;

    for (int it = 0; it < NT; ++it) {
        if (flags[(b * NT + it) * NT + jt] == 0) continue;   // block-uniform branch
        __syncthreads();
        for (int idx = t; idx < NK * 128; idx += 128)
            lfs[idx] = lf[((size_t)b * NK + (idx >> 7)) * HW_ + it * 128 + (idx & 127)];
        __syncthreads();
        const bf16* ap = aff + ((size_t)b * HW_ + it * 128) * HW_ + j;
        for (int ii = 0; ii < 128; ++ii) {
            float a = __bfloat162float(ap[(size_t)ii * HW_]);
#pragma unroll
            for (int k = 0; k < NK; ++k)
                acc[k] = fmaf(lfs[(k << 7) + ii], a, acc[k]);
        }
    }
    float inv = 1.0f / colsum[b * HW_ + j];
#pragma unroll
    for (int k = 0; k < NK; ++k)
        outp[((size_t)b * NK + k) * HW_ + j] = acc[k] * inv;
}

extern "C" void kernel_launch(void* const* d_in, const int* in_sizes, int n_in,
                              void* d_out, int out_size, void* d_ws, size_t ws_size,
                              hipStream_t stream) {
    const float* x4 = (const float*)d_in[0];
    const float* logits = (const float*)d_in[1];
    float* out = (float*)d_out;

    char* w = (char*)d_ws;
    size_t off = 0;
    auto take = [&](size_t bytes) {
        char* p = w + off;
        off += (bytes + 255) & ~(size_t)255;
        return p;
    };
    unsigned char* Xn8 = (unsigned char*)take((size_t)B_ * HW_ * C_);   // 32 MiB
    bf16* aff     = (bf16*)take((size_t)B_ * HW_ * HW_ * 2);            // 256 MiB
    // colsum, flags, sumsq contiguous (multiples of 256B) -> one memset
    float* colsum = (float*)take((size_t)B_ * HW_ * 4);
    int*   flags  = (int*)take((size_t)B_ * NT * NT * 4);
    float* sumsq  = (float*)take((size_t)B_ * HW_ * 4);
    float* lf1    = (float*)take((size_t)B_ * NK * HW_ * 4);

    hipMemsetAsync(colsum, 0, (size_t)B_ * HW_ * 4 + (size_t)B_ * NT * NT * 4 + (size_t)B_ * HW_ * 4, stream);

    knorm1<<<dim3(HW_ / 256, 8, B_), dim3(256), 0, stream>>>(x4, sumsq);
    ktrans<<<dim3(HW_ / 64, C_ / 64, B_), dim3(256), 0, stream>>>(x4, sumsq, Xn8);
    kgram <<<dim3(NTRI, B_), dim3(256), 0, stream>>>(Xn8, aff, colsum, flags);

    // pcm = 2 propagation rounds, colsum division fused into kprop epilogue
    kprop<<<dim3(NT, B_), dim3(128), 0, stream>>>(logits, aff, flags, colsum, lf1);
    kprop<<<dim3(NT, B_), dim3(128), 0, stream>>>(lf1, aff, flags, colsum, out);
}

// Round 6
// 367.718 us; speedup vs baseline: 4.7861x; 1.0753x over previous
//
#include <hip/hip_runtime.h>
#include <hip/hip_bf16.h>

#define B_  8
#define C_  1024
#define HW_ 4096
#define NK  21
#define NT  32          // HW_/128 tiles per dim
#define NTRI (NT * (NT + 1) / 2)   // 528 upper-triangle tiles

using bf16 = __hip_bfloat16;
typedef __attribute__((ext_vector_type(4))) float float4_;
typedef __attribute__((ext_vector_type(2))) long long2_;

// ---------------- kernel 1: partial sum-of-squares (split over C) ------------
__global__ __launch_bounds__(256) void knorm1(const float* __restrict__ x4, float* __restrict__ sumsq) {
    int t = threadIdx.x;
    int b = blockIdx.z;
    int c0 = blockIdx.y * 128;
    int j = blockIdx.x * 256 + t;
    const float* p = x4 + ((size_t)b * C_ + c0) * HW_ + j;
    float s = 0.f;
#pragma unroll 8
    for (int c = 0; c < 128; ++c) {
        float v = p[(size_t)c * HW_];
        s = fmaf(v, v, s);
    }
    atomicAdd(&sumsq[b * HW_ + j], s);
}

// ---------------- kernel 2: transpose + normalize -> Xn8 (fp8, interleaved K) -
// Within each 128-byte K-block, physical 16B chunk u = p*4+lk holds the 8B
// k-chunks of MFMA j=2p (bytes 0..7) and j=2p+1 (bytes 8..15) for lane group
// lk, i.e. global k = (2p+h)*32 + lk*8 + kb. This makes kgram's per-lane 16B
// fragment reads contiguous -> ds_read_b128.
__global__ __launch_bounds__(256) void ktrans(const float* __restrict__ x4, const float* __restrict__ sumsq,
                                              unsigned char* __restrict__ Xn8) {
    int b = blockIdx.z, ct = blockIdx.y, jt = blockIdx.x;
    int c0 = ct * 128, j0 = jt * 64;
    int t = threadIdx.x;
    __shared__ float tile[128][65];   // [c][j]

    int jl = t & 63, cl = t >> 6;
#pragma unroll
    for (int cc = 0; cc < 128; cc += 4)
        tile[cc + cl][jl] = x4[((size_t)b * C_ + c0 + cc + cl) * HW_ + j0 + jl];
    __syncthreads();

    int j = t >> 2, q = t & 3;
    int jg = j0 + j;
    float inv = 1.0f / fmaxf(sqrtf(sumsq[b * HW_ + jg]), 1e-12f);

#pragma unroll
    for (int pass = 0; pass < 2; ++pass) {
        int u = pass * 4 + q;          // phys chunk 0..7
        int p = u >> 2, lk = u & 3;
        unsigned int pk[4];
#pragma unroll
        for (int h = 0; h < 2; ++h) {
            int kbase = (2 * p + h) * 32 + lk * 8;
#pragma unroll
            for (int g = 0; g < 2; ++g) {
                float f0 = tile[kbase + g * 4 + 0][j] * inv;
                float f1 = tile[kbase + g * 4 + 1][j] * inv;
                float f2 = tile[kbase + g * 4 + 2][j] * inv;
                float f3 = tile[kbase + g * 4 + 3][j] * inv;
                unsigned int r = 0;
                r = __builtin_amdgcn_cvt_pk_fp8_f32(f0, f1, r, false);
                r = __builtin_amdgcn_cvt_pk_fp8_f32(f2, f3, r, true);
                pk[h * 2 + g] = r;
            }
        }
        *(uint4*)(Xn8 + ((size_t)b * HW_ + jg) * C_ + c0 + u * 16) =
            make_uint4(pk[0], pk[1], pk[2], pk[3]);
    }
}

// ---------------- kernel 3: symmetric gram (fp8 MFMA), upper-triangle tiles --
// 128x128 tile per block, BK=128 fp8, 4 waves (2x2), 4x4 frags of
// mfma_f32_16x16x32_fp8_fp8. LDS XOR-swizzled at 16B chunks with the FULL
// 3-bit row index (chunk ^ (r&7)); frag reads are ds_read_b128 (one read
// feeds two MFMAs via the interleaved-K Xn8 layout) -> conflict-free phases.
__global__ __launch_bounds__(256) void kgram(const unsigned char* __restrict__ Xn8, bf16* __restrict__ aff,
                                             float* __restrict__ colsum, int* __restrict__ flags) {
    int b = blockIdx.y;
    int p = blockIdx.x;
    int it = (int)((2.0f * NT + 1.0f - sqrtf((2.0f * NT + 1.0f) * (2.0f * NT + 1.0f) - 8.0f * (float)p)) * 0.5f);
    while (it > 0 && p < it * NT - it * (it - 1) / 2) --it;
    while (p >= (it + 1) * NT - (it + 1) * it / 2) ++it;
    int jt = it + p - (it * NT - it * (it - 1) / 2);

    int i0 = it * 128, j0 = jt * 128;
    int t = threadIdx.x, w = t >> 6, l = t & 63;
    int wr = w >> 1, wc = w & 1;
    int lrow = l & 15, lk = l >> 4;

    __shared__ __align__(16) unsigned char As[128 * 128];
    __shared__ __align__(16) unsigned char Bs[128 * 128];
    __shared__ int fl;

    const unsigned char* XA = Xn8 + ((size_t)b * HW_ + i0) * C_;
    const unsigned char* XB = Xn8 + ((size_t)b * HW_ + j0) * C_;

    int srow = l >> 3;        // row within 8-row issue group
    int sslot = l & 7;        // 16B LDS slot

    float4_ acc[4][4];
#pragma unroll
    for (int m = 0; m < 4; ++m)
#pragma unroll
        for (int n = 0; n < 4; ++n) acc[m][n] = {0.f, 0.f, 0.f, 0.f};

    for (int k0 = 0; k0 < C_; k0 += 128) {
        __syncthreads();
#pragma unroll
        for (int q = 0; q < 4; ++q) {
            int R = (w * 4 + q) * 8 + srow;           // 0..127
            int gp = sslot ^ (R & 7);
            __builtin_amdgcn_global_load_lds(
                (const __attribute__((address_space(1))) void*)(XA + (size_t)R * C_ + k0 + gp * 16),
                (__attribute__((address_space(3))) void*)(As + R * 128 + sslot * 16), 16, 0, 0);
            __builtin_amdgcn_global_load_lds(
                (const __attribute__((address_space(1))) void*)(XB + (size_t)R * C_ + k0 + gp * 16),
                (__attribute__((address_space(3))) void*)(Bs + R * 128 + sslot * 16), 16, 0, 0);
        }
        __syncthreads();
#pragma unroll
        for (int pp = 0; pp < 2; ++pp) {               // pair of MFMAs (j=2p, 2p+1)
            long2_ av[4], bv[4];
#pragma unroll
            for (int m = 0; m < 4; ++m) {
                int r = wr * 64 + m * 16 + lrow;
                av[m] = *(const long2_*)(As + r * 128 + ((pp * 4 + lk) ^ (r & 7)) * 16);
            }
#pragma unroll
            for (int n = 0; n < 4; ++n) {
                int r = wc * 64 + n * 16 + lrow;
                bv[n] = *(const long2_*)(Bs + r * 128 + ((pp * 4 + lk) ^ (r & 7)) * 16);
            }
#pragma unroll
            for (int m = 0; m < 4; ++m)
#pragma unroll
                for (int n = 0; n < 4; ++n) {
                    acc[m][n] = __builtin_amdgcn_mfma_f32_16x16x32_fp8_fp8(av[m].x, bv[n].x, acc[m][n], 0, 0, 0);
                    acc[m][n] = __builtin_amdgcn_mfma_f32_16x16x32_fp8_fp8(av[m].y, bv[n].y, acc[m][n], 0, 0, 0);
                }
        }
    }

    // tile nonzero flag: any raw value >= 0.5
    bool any = false;
#pragma unroll
    for (int m = 0; m < 4; ++m)
#pragma unroll
        for (int n = 0; n < 4; ++n)
#pragma unroll
            for (int r = 0; r < 4; ++r) any |= (acc[m][n][r] >= 0.5f);

    if (t == 0) fl = 0;
    __syncthreads();
    unsigned long long bal = __ballot(any);
    if (l == 0 && bal != 0ull) atomicOr(&fl, 1);
    __syncthreads();
    bool mirror = (it != jt);
    if (t == 0) {
        flags[(b * NT + it) * NT + jt] = fl;
        if (mirror) flags[(b * NT + jt) * NT + it] = fl;
    }

    if (fl) {
        size_t affb = (size_t)b * HW_ * HW_;
        float rsum[4][4];
#pragma unroll
        for (int m = 0; m < 4; ++m)
#pragma unroll
            for (int r = 0; r < 4; ++r) rsum[m][r] = 0.f;

#pragma unroll
        for (int n = 0; n < 4; ++n) {
            int j = j0 + wc * 64 + n * 16 + lrow;
            float cs = 0.f;
#pragma unroll
            for (int m = 0; m < 4; ++m) {
#pragma unroll
                for (int r = 0; r < 4; ++r) {
                    float v = acc[m][n][r];
                    v = fminf(fmaxf(v, 0.01f), 0.999f);
                    v = (v < 0.5f) ? 0.0f : v;
                    bf16 bb = __float2bfloat16(v);
                    int i = i0 + wr * 64 + m * 16 + lk * 4 + r;
                    aff[affb + (size_t)i * HW_ + j] = bb;
                    float bf = __bfloat162float(bb);
                    cs += bf;
                    rsum[m][r] += bf;
                    if (mirror) aff[affb + (size_t)j * HW_ + i] = bb;
                }
            }
            cs += __shfl_xor(cs, 16);
            cs += __shfl_xor(cs, 32);
            if (lk == 0) atomicAdd(&colsum[b * HW_ + j], cs);
        }
        if (mirror) {
#pragma unroll
            for (int m = 0; m < 4; ++m) {
#pragma unroll
                for (int r = 0; r < 4; ++r) {
                    float s = rsum[m][r];
                    s += __shfl_xor(s, 1);
                    s += __shfl_xor(s, 2);
                    s += __shfl_xor(s, 4);
                    s += __shfl_xor(s, 8);
                    if (lrow == 0) {
                        int i = i0 + wr * 64 + m * 16 + lk * 4 + r;
                        atomicAdd(&colsum[b * HW_ + i], s);
                    }
                }
            }
        }
    }
}

// ---------------- kernel 4: out[k][j] = (sum_i lf[k][i]*aff[i][j]) / colsum[j]
__global__ __launch_bounds__(128) void kprop(const float* __restrict__ lf, const bf16* __restrict__ aff,
                                             const int* __restrict__ flags, const float* __restrict__ colsum,
                                             float* __restrict__ outp) {
    int b = blockIdx.y, jt = blockIdx.x;
    int t = threadIdx.x;                 // 128 threads
    int j = jt * 128 + t;
    __shared__ float lfs[NK * 128];
    float acc[NK];
#pragma unroll
    for (int k = 0; k < NK; ++k) acc[k] = 0.f;

    for (int it = 0; it < NT; ++it) {
        if (flags[(b * NT + it) * NT + jt] == 0) continue;   // block-uniform branch
        __syncthreads();
        for (int idx = t; idx < NK * 128; idx += 128)
            lfs[idx] = lf[((size_t)b * NK + (idx >> 7)) * HW_ + it * 128 + (idx & 127)];
        __syncthreads();
        const bf16* ap = aff + ((size_t)b * HW_ + it * 128) * HW_ + j;
        for (int ii = 0; ii < 128; ++ii) {
            float a = __bfloat162float(ap[(size_t)ii * HW_]);
#pragma unroll
            for (int k = 0; k < NK; ++k)
                acc[k] = fmaf(lfs[(k << 7) + ii], a, acc[k]);
        }
    }
    float inv = 1.0f / colsum[b * HW_ + j];
#pragma unroll
    for (int k = 0; k < NK; ++k)
        outp[((size_t)b * NK + k) * HW_ + j] = acc[k] * inv;
}

extern "C" void kernel_launch(void* const* d_in, const int* in_sizes, int n_in,
                              void* d_out, int out_size, void* d_ws, size_t ws_size,
                              hipStream_t stream) {
    const float* x4 = (const float*)d_in[0];
    const float* logits = (const float*)d_in[1];
    float* out = (float*)d_out;

    char* w = (char*)d_ws;
    size_t off = 0;
    auto take = [&](size_t bytes) {
        char* p = w + off;
        off += (bytes + 255) & ~(size_t)255;
        return p;
    };
    unsigned char* Xn8 = (unsigned char*)take((size_t)B_ * HW_ * C_);   // 32 MiB
    bf16* aff     = (bf16*)take((size_t)B_ * HW_ * HW_ * 2);            // 256 MiB
    // colsum, flags, sumsq contiguous (multiples of 256B) -> one memset
    float* colsum = (float*)take((size_t)B_ * HW_ * 4);
    int*   flags  = (int*)take((size_t)B_ * NT * NT * 4);
    float* sumsq  = (float*)take((size_t)B_ * HW_ * 4);
    float* lf1    = (float*)take((size_t)B_ * NK * HW_ * 4);

    hipMemsetAsync(colsum, 0, (size_t)B_ * HW_ * 4 + (size_t)B_ * NT * NT * 4 + (size_t)B_ * HW_ * 4, stream);

    knorm1<<<dim3(HW_ / 256, 8, B_), dim3(256), 0, stream>>>(x4, sumsq);
    ktrans<<<dim3(HW_ / 64, C_ / 128, B_), dim3(256), 0, stream>>>(x4, sumsq, Xn8);
    kgram <<<dim3(NTRI, B_), dim3(256), 0, stream>>>(Xn8, aff, colsum, flags);

    // pcm = 2 propagation rounds, colsum division fused into kprop epilogue
    kprop<<<dim3(NT, B_), dim3(128), 0, stream>>>(logits, aff, flags, colsum, lf1);
    kprop<<<dim3(NT, B_), dim3(128), 0, stream>>>(lf1, aff, flags, colsum, out);
}

// Round 7
// 355.173 us; speedup vs baseline: 4.9551x; 1.0353x over previous
//
#include <hip/hip_runtime.h>
#include <hip/hip_bf16.h>

#define B_  8
#define C_  1024
#define HW_ 4096
#define NK  21
#define NT  32          // HW_/128 tiles per dim
#define NTRI (NT * (NT + 1) / 2)   // 528 upper-triangle tiles

using bf16 = __hip_bfloat16;
typedef __attribute__((ext_vector_type(4))) float float4_;
typedef __attribute__((ext_vector_type(8))) int int8v;

// ---- kernel 1: transpose + fp8-quantize (UNNORMALIZED) + sumsq reduction ----
// Xq[b][j][c] plain row-major fp8 e4m3. Normalization deferred to kgram's
// epilogue (rn_i*rn_j scaling) -- fp8 is log-scale so quantizing before or
// after normalization has identical relative error. sumsq computed here from
// the fp32 values (LDS reduce + one global atomic per column per c-chunk).
__global__ __launch_bounds__(256) void ktrans(const float* __restrict__ x4, float* __restrict__ sumsq,
                                              unsigned char* __restrict__ Xq) {
    int b = blockIdx.z, ct = blockIdx.y, jt = blockIdx.x;
    int c0 = ct * 128, j0 = jt * 64;
    int t = threadIdx.x;
    __shared__ float tile[128][65];   // [c][j]
    __shared__ float ssq[64];

    int jl = t & 63, cl = t >> 6;
    if (t < 64) ssq[t] = 0.f;
    __syncthreads();
    float part = 0.f;
#pragma unroll
    for (int cc = 0; cc < 128; cc += 4) {
        float v = x4[((size_t)b * C_ + c0 + cc + cl) * HW_ + j0 + jl];
        tile[cc + cl][jl] = v;
        part = fmaf(v, v, part);
    }
    atomicAdd(&ssq[jl], part);
    __syncthreads();

    // phase2: thread t -> column j = t>>2, 32-byte c-segment q = t&3
    int j = t >> 2, q = t & 3;
    int jg = j0 + j;
    unsigned int pk[8];
#pragma unroll
    for (int g = 0; g < 8; ++g) {
        float f0 = tile[q * 32 + g * 4 + 0][j];
        float f1 = tile[q * 32 + g * 4 + 1][j];
        float f2 = tile[q * 32 + g * 4 + 2][j];
        float f3 = tile[q * 32 + g * 4 + 3][j];
        unsigned int r = 0;
        r = __builtin_amdgcn_cvt_pk_fp8_f32(f0, f1, r, false);
        r = __builtin_amdgcn_cvt_pk_fp8_f32(f2, f3, r, true);
        pk[g] = r;
    }
    unsigned char* dst = Xq + ((size_t)b * HW_ + jg) * C_ + c0 + q * 32;
    *(uint4*)(dst)      = make_uint4(pk[0], pk[1], pk[2], pk[3]);
    *(uint4*)(dst + 16) = make_uint4(pk[4], pk[5], pk[6], pk[7]);

    if (t < 64) atomicAdd(&sumsq[b * HW_ + j0 + t], ssq[t]);
}

// ---- kernel 2: symmetric gram (MX-scaled fp8 K=128 MFMA), upper triangle ----
// 128x128 tile per block, BK=128, 4 waves (2x2), 4x4 frags of
// mfma_scale_f32_16x16x128_f8f6f4 (scale = 1.0 = 0x7F E8M0, broadcast bytes).
// LDS XOR-swizzled at 16B chunks (chunk ^ (r&7)) -> conflict-free ds_read_b128.
// Normalization (rn_i*rn_j) applied to the accumulator in the epilogue.
__global__ __launch_bounds__(256) void kgram(const unsigned char* __restrict__ Xq,
                                             const float* __restrict__ sumsq, bf16* __restrict__ aff,
                                             float* __restrict__ colsum, int* __restrict__ flags) {
    int b = blockIdx.y;
    int p = blockIdx.x;
    int it = (int)((2.0f * NT + 1.0f - sqrtf((2.0f * NT + 1.0f) * (2.0f * NT + 1.0f) - 8.0f * (float)p)) * 0.5f);
    while (it > 0 && p < it * NT - it * (it - 1) / 2) --it;
    while (p >= (it + 1) * NT - (it + 1) * it / 2) ++it;
    int jt = it + p - (it * NT - it * (it - 1) / 2);

    int i0 = it * 128, j0 = jt * 128;
    int t = threadIdx.x, w = t >> 6, l = t & 63;
    int wr = w >> 1, wc = w & 1;
    int lrow = l & 15, lk = l >> 4;

    __shared__ __align__(16) unsigned char As[128 * 128];
    __shared__ __align__(16) unsigned char Bs[128 * 128];
    __shared__ int fl;

    const unsigned char* XA = Xq + ((size_t)b * HW_ + i0) * C_;
    const unsigned char* XB = Xq + ((size_t)b * HW_ + j0) * C_;

    int srow = l >> 3;        // row within 8-row issue group
    int sslot = l & 7;        // 16B LDS slot

    float4_ acc[4][4];
#pragma unroll
    for (int m = 0; m < 4; ++m)
#pragma unroll
        for (int n = 0; n < 4; ++n) acc[m][n] = {0.f, 0.f, 0.f, 0.f};

    for (int k0 = 0; k0 < C_; k0 += 128) {
        __syncthreads();
#pragma unroll
        for (int q = 0; q < 4; ++q) {
            int R = (w * 4 + q) * 8 + srow;           // 0..127
            int gp = sslot ^ (R & 7);
            __builtin_amdgcn_global_load_lds(
                (const __attribute__((address_space(1))) void*)(XA + (size_t)R * C_ + k0 + gp * 16),
                (__attribute__((address_space(3))) void*)(As + R * 128 + sslot * 16), 16, 0, 0);
            __builtin_amdgcn_global_load_lds(
                (const __attribute__((address_space(1))) void*)(XB + (size_t)R * C_ + k0 + gp * 16),
                (__attribute__((address_space(3))) void*)(Bs + R * 128 + sslot * 16), 16, 0, 0);
        }
        __syncthreads();

        int8v av[4], bv[4];
#pragma unroll
        for (int m = 0; m < 4; ++m) {
            int r = wr * 64 + m * 16 + lrow;
            uint4 lo = *(const uint4*)(As + r * 128 + (((lk * 2) ^ (r & 7)) * 16));
            uint4 hi = *(const uint4*)(As + r * 128 + (((lk * 2 + 1) ^ (r & 7)) * 16));
            int8v v; v[0] = lo.x; v[1] = lo.y; v[2] = lo.z; v[3] = lo.w;
            v[4] = hi.x; v[5] = hi.y; v[6] = hi.z; v[7] = hi.w;
            av[m] = v;
        }
#pragma unroll
        for (int n = 0; n < 4; ++n) {
            int r = wc * 64 + n * 16 + lrow;
            uint4 lo = *(const uint4*)(Bs + r * 128 + (((lk * 2) ^ (r & 7)) * 16));
            uint4 hi = *(const uint4*)(Bs + r * 128 + (((lk * 2 + 1) ^ (r & 7)) * 16));
            int8v v; v[0] = lo.x; v[1] = lo.y; v[2] = lo.z; v[3] = lo.w;
            v[4] = hi.x; v[5] = hi.y; v[6] = hi.z; v[7] = hi.w;
            bv[n] = v;
        }
#pragma unroll
        for (int m = 0; m < 4; ++m)
#pragma unroll
            for (int n = 0; n < 4; ++n)
                acc[m][n] = __builtin_amdgcn_mfma_scale_f32_16x16x128_f8f6f4(
                    av[m], bv[n], acc[m][n], 0, 0, 0, 0x7f7f7f7f, 0, 0x7f7f7f7f);
    }

    // epilogue: apply deferred normalization rn_i * rn_j to the accumulators
    float rnj[4], rni[4][4];
#pragma unroll
    for (int n = 0; n < 4; ++n) {
        int j = j0 + wc * 64 + n * 16 + lrow;
        rnj[n] = 1.0f / fmaxf(sqrtf(sumsq[b * HW_ + j]), 1e-12f);
    }
#pragma unroll
    for (int m = 0; m < 4; ++m)
#pragma unroll
        for (int r = 0; r < 4; ++r) {
            int i = i0 + wr * 64 + m * 16 + lk * 4 + r;
            rni[m][r] = 1.0f / fmaxf(sqrtf(sumsq[b * HW_ + i]), 1e-12f);
        }
#pragma unroll
    for (int m = 0; m < 4; ++m)
#pragma unroll
        for (int n = 0; n < 4; ++n)
#pragma unroll
            for (int r = 0; r < 4; ++r)
                acc[m][n][r] *= rni[m][r] * rnj[n];

    // tile nonzero flag: any value >= 0.5
    bool any = false;
#pragma unroll
    for (int m = 0; m < 4; ++m)
#pragma unroll
        for (int n = 0; n < 4; ++n)
#pragma unroll
            for (int r = 0; r < 4; ++r) any |= (acc[m][n][r] >= 0.5f);

    if (t == 0) fl = 0;
    __syncthreads();
    unsigned long long bal = __ballot(any);
    if (l == 0 && bal != 0ull) atomicOr(&fl, 1);
    __syncthreads();
    bool mirror = (it != jt);
    if (t == 0) {
        flags[(b * NT + it) * NT + jt] = fl;
        if (mirror) flags[(b * NT + jt) * NT + it] = fl;
    }

    if (fl) {
        size_t affb = (size_t)b * HW_ * HW_;
        float rsum[4][4];
#pragma unroll
        for (int m = 0; m < 4; ++m)
#pragma unroll
            for (int r = 0; r < 4; ++r) rsum[m][r] = 0.f;

#pragma unroll
        for (int n = 0; n < 4; ++n) {
            int j = j0 + wc * 64 + n * 16 + lrow;
            float cs = 0.f;
#pragma unroll
            for (int m = 0; m < 4; ++m) {
#pragma unroll
                for (int r = 0; r < 4; ++r) {
                    float v = acc[m][n][r];
                    v = fminf(fmaxf(v, 0.01f), 0.999f);
                    v = (v < 0.5f) ? 0.0f : v;
                    bf16 bb = __float2bfloat16(v);
                    int i = i0 + wr * 64 + m * 16 + lk * 4 + r;
                    aff[affb + (size_t)i * HW_ + j] = bb;
                    float bf = __bfloat162float(bb);
                    cs += bf;
                    rsum[m][r] += bf;
                    if (mirror) aff[affb + (size_t)j * HW_ + i] = bb;
                }
            }
            cs += __shfl_xor(cs, 16);
            cs += __shfl_xor(cs, 32);
            if (lk == 0) atomicAdd(&colsum[b * HW_ + j], cs);
        }
        if (mirror) {
#pragma unroll
            for (int m = 0; m < 4; ++m) {
#pragma unroll
                for (int r = 0; r < 4; ++r) {
                    float s = rsum[m][r];
                    s += __shfl_xor(s, 1);
                    s += __shfl_xor(s, 2);
                    s += __shfl_xor(s, 4);
                    s += __shfl_xor(s, 8);
                    if (lrow == 0) {
                        int i = i0 + wr * 64 + m * 16 + lk * 4 + r;
                        atomicAdd(&colsum[b * HW_ + i], s);
                    }
                }
            }
        }
    }
}

// ---- kernel 3: out[k][j] = (sum_i lf[k][i]*aff[i][j]) / colsum[j] -----------
__global__ __launch_bounds__(128) void kprop(const float* __restrict__ lf, const bf16* __restrict__ aff,
                                             const int* __restrict__ flags, const float* __restrict__ colsum,
                                             float* __restrict__ outp) {
    int b = blockIdx.y, jt = blockIdx.x;
    int t = threadIdx.x;                 // 128 threads
    int j = jt * 128 + t;
    __shared__ float lfs[NK * 128];
    float acc[NK];
#pragma unroll
    for (int k = 0; k < NK; ++k) acc[k] = 0.f;

    for (int it = 0; it < NT; ++it) {
        if (flags[(b * NT + it) * NT + jt] == 0) continue;   // block-uniform branch
        __syncthreads();
        for (int idx = t; idx < NK * 128; idx += 128)
            lfs[idx] = lf[((size_t)b * NK + (idx >> 7)) * HW_ + it * 128 + (idx & 127)];
        __syncthreads();
        const bf16* ap = aff + ((size_t)b * HW_ + it * 128) * HW_ + j;
        for (int ii = 0; ii < 128; ++ii) {
            float a = __bfloat162float(ap[(size_t)ii * HW_]);
#pragma unroll
            for (int k = 0; k < NK; ++k)
                acc[k] = fmaf(lfs[(k << 7) + ii], a, acc[k]);
        }
    }
    float inv = 1.0f / colsum[b * HW_ + j];
#pragma unroll
    for (int k = 0; k < NK; ++k)
        outp[((size_t)b * NK + k) * HW_ + j] = acc[k] * inv;
}

extern "C" void kernel_launch(void* const* d_in, const int* in_sizes, int n_in,
                              void* d_out, int out_size, void* d_ws, size_t ws_size,
                              hipStream_t stream) {
    const float* x4 = (const float*)d_in[0];
    const float* logits = (const float*)d_in[1];
    float* out = (float*)d_out;

    char* w = (char*)d_ws;
    size_t off = 0;
    auto take = [&](size_t bytes) {
        char* p = w + off;
        off += (bytes + 255) & ~(size_t)255;
        return p;
    };
    unsigned char* Xq = (unsigned char*)take((size_t)B_ * HW_ * C_);    // 32 MiB
    bf16* aff     = (bf16*)take((size_t)B_ * HW_ * HW_ * 2);            // 256 MiB
    // colsum, flags, sumsq contiguous (multiples of 256B) -> one memset
    float* colsum = (float*)take((size_t)B_ * HW_ * 4);
    int*   flags  = (int*)take((size_t)B_ * NT * NT * 4);
    float* sumsq  = (float*)take((size_t)B_ * HW_ * 4);
    float* lf1    = (float*)take((size_t)B_ * NK * HW_ * 4);

    hipMemsetAsync(colsum, 0, (size_t)B_ * HW_ * 4 + (size_t)B_ * NT * NT * 4 + (size_t)B_ * HW_ * 4, stream);

    ktrans<<<dim3(HW_ / 64, C_ / 128, B_), dim3(256), 0, stream>>>(x4, sumsq, Xq);
    kgram <<<dim3(NTRI, B_), dim3(256), 0, stream>>>(Xq, sumsq, aff, colsum, flags);

    // pcm = 2 propagation rounds, colsum division fused into kprop epilogue
    kprop<<<dim3(NT, B_), dim3(128), 0, stream>>>(logits, aff, flags, colsum, lf1);
    kprop<<<dim3(NT, B_), dim3(128), 0, stream>>>(lf1, aff, flags, colsum, out);
}